// Round 1
// baseline (1369.601 us; speedup 1.0000x reference)
//
#include <hip/hip_runtime.h>
#include <cstddef>

#define NODES 10000
#define EDGES 320000

// ---------------- CSR build (by dst) ----------------
__global__ void count_kernel(const int* __restrict__ dst, int E, int* __restrict__ counts){
    int e = blockIdx.x*blockDim.x + threadIdx.x;
    if (e < E) atomicAdd(&counts[dst[e]], 1);
}

__global__ __launch_bounds__(1024) void scan_kernel(const int* __restrict__ counts,
                                                    int* __restrict__ rowptr, int N){
    __shared__ int part[1024];
    int t = threadIdx.x;
    int chunk = (N + 1023) / 1024;
    int b0 = t * chunk;
    int s = 0;
    for (int i=0;i<chunk;i++){ int idx=b0+i; if (idx<N) s += counts[idx]; }
    part[t] = s;
    __syncthreads();
    for (int off=1; off<1024; off<<=1){
        int v = (t>=off) ? part[t-off] : 0;
        __syncthreads();
        part[t] += v;
        __syncthreads();
    }
    int excl = (t==0) ? 0 : part[t-1];
    for (int i=0;i<chunk;i++){
        int idx=b0+i;
        if (idx<N){ rowptr[idx]=excl; excl += counts[idx]; }
    }
    if (t==1023) rowptr[N] = part[1023];
}

__global__ void fill_kernel(const int* __restrict__ src, const int* __restrict__ dst, int E,
                            int* __restrict__ cursor, int* __restrict__ col){
    int e = blockIdx.x*blockDim.x + threadIdx.x;
    if (e < E){
        int d = dst[e];
        int p = atomicAdd(&cursor[d], 1);
        col[p] = src[e];
    }
}

// ---------------- generic fp32 GEMM: C[M,N] = A[M,K] @ B[K,N] (+bias, relu) ----------------
// requires N % 64 == 0, K % 16 == 0 (true for all shapes here); M guarded.
__global__ __launch_bounds__(256) void gemm_f32(const float* __restrict__ A, const float* __restrict__ B,
        float* __restrict__ C, int Mr, int Nr, int Kr, const float* __restrict__ bias, int relu)
{
    __shared__ float As[16][68];   // transposed A tile, padded stride (float4-aligned, conflict-light)
    __shared__ float Bs[16][64];
    int t  = threadIdx.x;
    int tx = t & 15, ty = t >> 4;
    int m0 = blockIdx.y * 64, n0 = blockIdx.x * 64;
    int ar = t >> 2;            // 0..63 (tile row)
    int ak = (t & 3) * 4;       // 0,4,8,12
    int bk = t >> 4;            // 0..15
    int bn = (t & 15) * 4;      // 0..60
    float acc[4][4];
    #pragma unroll
    for (int i=0;i<4;i++)
      #pragma unroll
      for (int j=0;j<4;j++) acc[i][j]=0.f;

    for (int k0=0; k0<Kr; k0+=16){
        float4 av = make_float4(0.f,0.f,0.f,0.f);
        if (m0 + ar < Mr) av = *(const float4*)&A[(size_t)(m0+ar)*Kr + k0 + ak];
        As[ak+0][ar]=av.x; As[ak+1][ar]=av.y; As[ak+2][ar]=av.z; As[ak+3][ar]=av.w;
        *(float4*)&Bs[bk][bn] = *(const float4*)&B[(size_t)(k0+bk)*Nr + n0 + bn];
        __syncthreads();
        #pragma unroll
        for (int kk=0;kk<16;kk++){
            float4 a = *(const float4*)&As[kk][ty*4];
            float4 b = *(const float4*)&Bs[kk][tx*4];
            float aa[4] = {a.x,a.y,a.z,a.w};
            float bb[4] = {b.x,b.y,b.z,b.w};
            #pragma unroll
            for (int i=0;i<4;i++)
              #pragma unroll
              for (int j=0;j<4;j++) acc[i][j] += aa[i]*bb[j];
        }
        __syncthreads();
    }
    #pragma unroll
    for (int i=0;i<4;i++){
        int m = m0 + ty*4 + i;
        if (m >= Mr) continue;
        alignas(16) float vv[4];
        #pragma unroll
        for (int j=0;j<4;j++){
            float val = acc[i][j];
            if (bias) val += bias[n0 + tx*4 + j];
            if (relu) val = val > 0.f ? val : 0.f;
            vv[j] = val;
        }
        *(float4*)&C[(size_t)m*Nr + n0 + tx*4] = *(float4*)vv;
    }
}

// ---------------- attention logits: al_s[n,h] = <xp[n,h,:], a_src[h,:]>, same for dst ----------------
__global__ __launch_bounds__(256) void al_kernel(const float* __restrict__ xp,
        const float* __restrict__ a_src, const float* __restrict__ a_dst,
        float* __restrict__ als, float* __restrict__ ald, int N, int H, int C)
{
    int n = blockIdx.x;
    int t = threadIdx.x;
    __shared__ float rs[4], rd[4];
    for (int h=0;h<H;h++){
        float ps=0.f, pd=0.f;
        for (int c=t;c<C;c+=256){
            float v = xp[(size_t)n*H*C + (size_t)h*C + c];
            ps += v * a_src[h*C+c];
            pd += v * a_dst[h*C+c];
        }
        #pragma unroll
        for (int off=32; off; off>>=1){
            ps += __shfl_down(ps, off);
            pd += __shfl_down(pd, off);
        }
        if ((t & 63) == 0){ rs[t>>6]=ps; rd[t>>6]=pd; }
        __syncthreads();
        if (t==0){
            als[n*H+h] = rs[0]+rs[1]+rs[2]+rs[3];
            ald[n*H+h] = rd[0]+rd[1]+rd[2]+rd[3];
        }
        __syncthreads();
    }
}

// ---------------- GAT aggregation per dst node (softmax over in-edges + weighted sum) ----------------
template<int H, int C>
__global__ __launch_bounds__(256) void gat_agg(const float* __restrict__ xp,
        const float* __restrict__ als, const float* __restrict__ ald,
        const int* __restrict__ rowptr, const int* __restrict__ col,
        const float* __restrict__ bias, float* __restrict__ out, int N)
{
    constexpr int W  = H*C;
    constexpr int PC = W/256;
    constexpr int CH = 128;
    int n = blockIdx.x;
    int t = threadIdx.x;
    int beg = rowptr[n], end = rowptr[n+1];
    int deg = end - beg;
    __shared__ float red[4];
    __shared__ float m_sh[H], den_sh[H];
    __shared__ int   sidx[CH];
    __shared__ float salpha[CH*H];

    float aldn[H];
    #pragma unroll
    for (int h=0;h<H;h++) aldn[h] = ald[n*H+h];

    for (int h=0;h<H;h++){
        float mx = -1e30f;
        for (int i=t;i<deg;i+=256){
            int s = col[beg+i];
            float e = als[s*H+h] + aldn[h];
            e = e>0.f ? e : 0.2f*e;
            mx = fmaxf(mx, e);
        }
        #pragma unroll
        for (int off=32; off; off>>=1) mx = fmaxf(mx, __shfl_down(mx,off));
        if ((t&63)==0) red[t>>6]=mx;
        __syncthreads();
        if (t==0) m_sh[h] = fmaxf(fmaxf(red[0],red[1]), fmaxf(red[2],red[3]));
        __syncthreads();
        float m = m_sh[h];
        float sm = 0.f;
        for (int i=t;i<deg;i+=256){
            int s = col[beg+i];
            float e = als[s*H+h] + aldn[h];
            e = e>0.f ? e : 0.2f*e;
            sm += expf(e - m);
        }
        #pragma unroll
        for (int off=32; off; off>>=1) sm += __shfl_down(sm,off);
        if ((t&63)==0) red[t>>6]=sm;
        __syncthreads();
        if (t==0) den_sh[h] = red[0]+red[1]+red[2]+red[3];
        __syncthreads();
    }

    float acc[PC];
    #pragma unroll
    for (int j=0;j<PC;j++) acc[j]=0.f;
    float invden[H], msh[H];
    #pragma unroll
    for (int h=0;h<H;h++){ invden[h] = 1.f/(den_sh[h]+1e-16f); msh[h]=m_sh[h]; }

    for (int c0=0;c0<deg;c0+=CH){
        int cl = min(CH, deg-c0);
        __syncthreads();
        if (t < cl){
            int s = col[beg+c0+t];
            sidx[t] = s;
            #pragma unroll
            for (int h=0;h<H;h++){
                float e = als[s*H+h] + aldn[h];
                e = e>0.f ? e : 0.2f*e;
                salpha[t*H+h] = expf(e - msh[h]) * invden[h];
            }
        }
        __syncthreads();
        for (int i=0;i<cl;i++){
            int s = sidx[i];
            const float* row = xp + (size_t)s*W;
            #pragma unroll
            for (int j=0;j<PC;j++){
                int cidx = t + j*256;
                acc[j] += salpha[i*H + (cidx/C)] * row[cidx];
            }
        }
    }
    #pragma unroll
    for (int j=0;j<PC;j++){
        int cidx = t + j*256;
        float v = acc[j] + bias[cidx];
        out[(size_t)n*W + cidx] = v>0.f ? v : 0.f;
    }
}

// ---------------- final: C[M,D] = X[M,64] @ Y[D,64]^T ----------------
__global__ __launch_bounds__(256) void gemm_nt64(const float* __restrict__ X, const float* __restrict__ Y,
        float* __restrict__ C, int Mr, int Dr)
{
    __shared__ float Xs[128][68];
    __shared__ float Ys[128][68];
    int t  = threadIdx.x;
    int m0 = blockIdx.y * 128, d0 = blockIdx.x * 128;
    int lr = t >> 4;            // 0..15
    int lq = (t & 15) * 4;      // 0..60
    #pragma unroll
    for (int i=0;i<8;i++){
        int row = lr + i*16;
        float4 xv = make_float4(0.f,0.f,0.f,0.f), yv = make_float4(0.f,0.f,0.f,0.f);
        if (m0+row < Mr) xv = *(const float4*)&X[(size_t)(m0+row)*64 + lq];
        if (d0+row < Dr) yv = *(const float4*)&Y[(size_t)(d0+row)*64 + lq];
        *(float4*)&Xs[row][lq] = xv;
        *(float4*)&Ys[row][lq] = yv;
    }
    __syncthreads();
    int tx = t & 15, ty = t >> 4;
    float acc[8][8];
    #pragma unroll
    for (int i=0;i<8;i++)
      #pragma unroll
      for (int j=0;j<8;j++) acc[i][j]=0.f;

    for (int k=0;k<64;k+=4){
        float4 xa[8], yb[8];
        #pragma unroll
        for (int i=0;i<8;i++) xa[i] = *(const float4*)&Xs[ty*8+i][k];
        #pragma unroll
        for (int j=0;j<8;j++) yb[j] = *(const float4*)&Ys[tx*8+j][k];
        #pragma unroll
        for (int i=0;i<8;i++)
          #pragma unroll
          for (int j=0;j<8;j++)
            acc[i][j] += xa[i].x*yb[j].x + xa[i].y*yb[j].y + xa[i].z*yb[j].z + xa[i].w*yb[j].w;
    }
    #pragma unroll
    for (int i=0;i<8;i++){
        int m = m0 + ty*8 + i;
        if (m >= Mr) continue;
        #pragma unroll
        for (int j4=0;j4<8;j4+=4){
            int nn = d0 + tx*8 + j4;
            if (nn >= Dr) continue;
            alignas(16) float vv[4] = {acc[i][j4],acc[i][j4+1],acc[i][j4+2],acc[i][j4+3]};
            *(float4*)&C[(size_t)m*Dr + nn] = *(float4*)vv;
        }
    }
}

extern "C" void kernel_launch(void* const* d_in, const int* in_sizes, int n_in,
                              void* d_out, int out_size, void* d_ws, size_t ws_size,
                              hipStream_t stream)
{
    const float* x_m  = (const float*)d_in[0];
    const float* x_d  = (const float*)d_in[1];
    const int*   eix  = (const int*)d_in[2];
    const int*   eiy  = (const int*)d_in[3];
    const float* Wx1  = (const float*)d_in[4];
    const float* ax1s = (const float*)d_in[5];
    const float* ax1d = (const float*)d_in[6];
    const float* bx1  = (const float*)d_in[7];
    const float* Wx2  = (const float*)d_in[8];
    const float* ax2s = (const float*)d_in[9];
    const float* ax2d = (const float*)d_in[10];
    const float* bx2  = (const float*)d_in[11];
    const float* Wy1  = (const float*)d_in[12];
    const float* ay1s = (const float*)d_in[13];
    const float* ay1d = (const float*)d_in[14];
    const float* by1  = (const float*)d_in[15];
    const float* Wy2  = (const float*)d_in[16];
    const float* ay2s = (const float*)d_in[17];
    const float* ay2d = (const float*)d_in[18];
    const float* by2  = (const float*)d_in[19];
    const float* lwx1 = (const float*)d_in[20];
    const float* lbx1 = (const float*)d_in[21];
    const float* lwx2 = (const float*)d_in[22];
    const float* lbx2 = (const float*)d_in[23];
    const float* lwx3 = (const float*)d_in[24];
    const float* lbx3 = (const float*)d_in[25];
    const float* lwy1 = (const float*)d_in[26];
    const float* lby1 = (const float*)d_in[27];
    const float* lwy2 = (const float*)d_in[28];
    const float* lby2 = (const float*)d_in[29];
    const float* lwy3 = (const float*)d_in[30];
    const float* lby3 = (const float*)d_in[31];

    const int N = NODES, E = EDGES;
    char* ws = (char*)d_ws;
    size_t off = 0;
    auto alloc = [&](size_t bytes)->char*{
        size_t a = (off + 255) & ~(size_t)255;
        off = a + bytes;
        return ws + a;
    };
    int* rowptr   = (int*)alloc((size_t)(N+1)*sizeof(int));
    int* cursor   = (int*)alloc((size_t)N*sizeof(int));
    int* counts   = (int*)alloc((size_t)N*sizeof(int));
    int* colidx   = (int*)alloc((size_t)E*sizeof(int));
    float* xp     = (float*)alloc((size_t)N*512*sizeof(float));
    float* bufA   = (float*)alloc((size_t)N*512*sizeof(float));
    float* bufB   = (float*)alloc((size_t)N*256*sizeof(float));
    float* als    = (float*)alloc((size_t)N*2*sizeof(float));
    float* aldv   = (float*)alloc((size_t)N*2*sizeof(float));
    float* xf     = (float*)alloc((size_t)N*64*sizeof(float));
    float* yf     = (float*)alloc((size_t)N*64*sizeof(float));

    auto run_graph = [&](const float* xin, const int* ei,
                         const float* W1, const float* a1s, const float* a1d, const float* b1,
                         const float* W2, const float* a2s, const float* a2d, const float* b2,
                         const float* lw1, const float* lb1, const float* lw2, const float* lb2,
                         const float* lw3, const float* lb3, float* outv)
    {
        const int* srcp = ei;
        const int* dstp = ei + E;
        hipMemsetAsync(counts, 0, (size_t)N*sizeof(int), stream);
        count_kernel<<<(E+255)/256, 256, 0, stream>>>(dstp, E, counts);
        scan_kernel<<<1, 1024, 0, stream>>>(counts, rowptr, N);
        hipMemcpyAsync(cursor, rowptr, (size_t)N*sizeof(int), hipMemcpyDeviceToDevice, stream);
        fill_kernel<<<(E+255)/256, 256, 0, stream>>>(srcp, dstp, E, cursor, colidx);
        // layer 1: H=2, C=256 (in 256 -> out 512)
        gemm_f32<<<dim3(512/64, (N+63)/64), 256, 0, stream>>>(xin, W1, xp, N, 512, 256, nullptr, 0);
        al_kernel<<<N, 256, 0, stream>>>(xp, a1s, a1d, als, aldv, N, 2, 256);
        gat_agg<2,256><<<N, 256, 0, stream>>>(xp, als, aldv, rowptr, colidx, b1, bufA, N);
        // layer 2: H=1, C=256 (in 512 -> out 256)
        gemm_f32<<<dim3(256/64, (N+63)/64), 256, 0, stream>>>(bufA, W2, xp, N, 256, 512, nullptr, 0);
        al_kernel<<<N, 256, 0, stream>>>(xp, a2s, a2d, als, aldv, N, 1, 256);
        gat_agg<1,256><<<N, 256, 0, stream>>>(xp, als, aldv, rowptr, colidx, b2, bufB, N);
        // MLP head: 256 -> 256 -> 128 -> 64, all relu
        gemm_f32<<<dim3(256/64, (N+63)/64), 256, 0, stream>>>(bufB, lw1, bufA, N, 256, 256, lb1, 1);
        gemm_f32<<<dim3(128/64, (N+63)/64), 256, 0, stream>>>(bufA, lw2, xp,   N, 128, 256, lb2, 1);
        gemm_f32<<<dim3(64/64,  (N+63)/64), 256, 0, stream>>>(xp,   lw3, outv, N, 64,  128, lb3, 1);
    };

    run_graph(x_m, eix, Wx1, ax1s, ax1d, bx1, Wx2, ax2s, ax2d, bx2,
              lwx1, lbx1, lwx2, lbx2, lwx3, lbx3, xf);
    run_graph(x_d, eiy, Wy1, ay1s, ay1d, by1, Wy2, ay2s, ay2d, by2,
              lwy1, lby1, lwy2, lby2, lwy3, lby3, yf);

    gemm_nt64<<<dim3((N+127)/128, (N+127)/128), 256, 0, stream>>>(xf, yf, (float*)d_out, N, N);
}

// Round 2
// 1258.471 us; speedup vs baseline: 1.0883x; 1.0883x over previous
//
#include <hip/hip_runtime.h>
#include <cstddef>

#define NODES 10000
#define EDGES 320000

typedef __attribute__((ext_vector_type(8))) short bf16x8;
typedef __attribute__((ext_vector_type(4))) float f32x4;

__device__ inline short bf16rn(float x){
    union { float f; unsigned u; } v; v.f = x;
    unsigned r = (v.u + 0x7FFFu + ((v.u >> 16) & 1u)) >> 16;
    return (short)r;
}
__device__ inline float bf16tof(short h){
    union { float f; unsigned u; } v; v.u = ((unsigned)(unsigned short)h) << 16;
    return v.f;
}

// ---------------- CSR build (by dst) ----------------
__global__ void count_kernel(const int* __restrict__ dst, int E, int* __restrict__ counts){
    int e = blockIdx.x*blockDim.x + threadIdx.x;
    if (e < E) atomicAdd(&counts[dst[e]], 1);
}

__global__ __launch_bounds__(1024) void scan_kernel(const int* __restrict__ counts,
                                                    int* __restrict__ rowptr, int N){
    __shared__ int part[1024];
    int t = threadIdx.x;
    int chunk = (N + 1023) / 1024;
    int b0 = t * chunk;
    int s = 0;
    for (int i=0;i<chunk;i++){ int idx=b0+i; if (idx<N) s += counts[idx]; }
    part[t] = s;
    __syncthreads();
    for (int off=1; off<1024; off<<=1){
        int v = (t>=off) ? part[t-off] : 0;
        __syncthreads();
        part[t] += v;
        __syncthreads();
    }
    int excl = (t==0) ? 0 : part[t-1];
    for (int i=0;i<chunk;i++){
        int idx=b0+i;
        if (idx<N){ rowptr[idx]=excl; excl += counts[idx]; }
    }
    if (t==1023) rowptr[N] = part[1023];
}

__global__ void fill_kernel(const int* __restrict__ src, const int* __restrict__ dst, int E,
                            int* __restrict__ cursor, int* __restrict__ col){
    int e = blockIdx.x*blockDim.x + threadIdx.x;
    if (e < E){
        int d = dst[e];
        int p = atomicAdd(&cursor[d], 1);
        col[p] = src[e];
    }
}

// ---------------- weight transpose + bf16 split: B[K,N] fp32 -> Bt_hi/Bt_lo [N,K] bf16 ----------------
// K, N multiples of 32.
__global__ __launch_bounds__(256) void splitT(const float* __restrict__ B,
        short* __restrict__ Bth, short* __restrict__ Btl, int K, int N)
{
    __shared__ float tile[32][33];
    int tx = threadIdx.x, ty = threadIdx.y;   // 32 x 8
    int n0 = blockIdx.x * 32, k0 = blockIdx.y * 32;
    #pragma unroll
    for (int r=0;r<4;r++){
        int k = ty + r*8;
        tile[k][tx] = B[(size_t)(k0+k)*N + n0 + tx];
    }
    __syncthreads();
    #pragma unroll
    for (int r=0;r<4;r++){
        int n = ty + r*8;
        float v = tile[tx][n];
        short h = bf16rn(v);
        short l = bf16rn(v - bf16tof(h));
        Bth[(size_t)(n0+n)*K + k0 + tx] = h;
        Btl[(size_t)(n0+n)*K + k0 + tx] = l;
    }
}

// ---------------- fp32 [n] -> hi/lo bf16 [n] (n % 4 == 0) ----------------
__global__ void split_rows(const float* __restrict__ in, short* __restrict__ hi,
                           short* __restrict__ lo, int n)
{
    int i = (blockIdx.x*blockDim.x + threadIdx.x) * 4;
    if (i >= n) return;
    float4 v = *(const float4*)&in[i];
    short h0=bf16rn(v.x), h1=bf16rn(v.y), h2=bf16rn(v.z), h3=bf16rn(v.w);
    short4 hv; hv.x=h0; hv.y=h1; hv.z=h2; hv.w=h3;
    short4 lv; lv.x=bf16rn(v.x-bf16tof(h0)); lv.y=bf16rn(v.y-bf16tof(h1));
    lv.z=bf16rn(v.z-bf16tof(h2)); lv.w=bf16rn(v.w-bf16tof(h3));
    *(short4*)&hi[i] = hv;
    *(short4*)&lo[i] = lv;
}

// ---------------- 3xBF16-split MFMA GEMM: C[M,N] = A[M,K] @ Bt[N,K]^T (+bias, relu) ----------------
// A fp32 row-major (split in-kernel). Bt pre-split bf16 [N,K]. Kr % 64 == 0. M, N guarded.
__global__ __launch_bounds__(256) void gemm_split(
    const float* __restrict__ A,
    const short* __restrict__ Bh, const short* __restrict__ Bl,
    float* __restrict__ C, const float* __restrict__ bias,
    int Mr, int Nr, int Kr, int relu)
{
    constexpr int LD = 88;   // 176B row stride: 16B-aligned, 12r mod 32 bank spread
    __shared__ short Ash[64][LD], Asl[64][LD], Bsh[64][LD], Bsl[64][LD];
    int t = threadIdx.x;
    int lane = t & 63, wave = t >> 6;
    int wm = (wave >> 1) * 32, wn = (wave & 1) * 32;
    int m0 = blockIdx.y * 64, n0 = blockIdx.x * 64;

    f32x4 acc[2][2];
    #pragma unroll
    for (int i=0;i<2;i++)
      #pragma unroll
      for (int j=0;j<2;j++)
        #pragma unroll
        for (int r=0;r<4;r++) acc[i][j][r] = 0.f;

    int ar = t >> 4;            // 0..15
    int ac = (t & 15) * 4;      // 0..60
    int br = t >> 3;            // 0..31
    int bc = (t & 7) * 8;       // 0..56

    for (int k0 = 0; k0 < Kr; k0 += 64){
        // stage A (fp32 -> hi/lo bf16)
        #pragma unroll
        for (int rep = 0; rep < 4; rep++){
            int row = ar + rep*16;
            float4 v = make_float4(0.f,0.f,0.f,0.f);
            if (m0 + row < Mr) v = *(const float4*)&A[(size_t)(m0+row)*Kr + k0 + ac];
            short h0=bf16rn(v.x), h1=bf16rn(v.y), h2=bf16rn(v.z), h3=bf16rn(v.w);
            short4 hv; hv.x=h0; hv.y=h1; hv.z=h2; hv.w=h3;
            short4 lv; lv.x=bf16rn(v.x-bf16tof(h0)); lv.y=bf16rn(v.y-bf16tof(h1));
            lv.z=bf16rn(v.z-bf16tof(h2)); lv.w=bf16rn(v.w-bf16tof(h3));
            *(short4*)&Ash[row][ac] = hv;
            *(short4*)&Asl[row][ac] = lv;
        }
        // stage B (pre-split bf16 [N,K])
        #pragma unroll
        for (int rep = 0; rep < 2; rep++){
            int row = br + rep*32;
            int gn = n0 + row;
            int4 hv = make_int4(0,0,0,0), lv = make_int4(0,0,0,0);
            if (gn < Nr){
                hv = *(const int4*)&Bh[(size_t)gn*Kr + k0 + bc];
                lv = *(const int4*)&Bl[(size_t)gn*Kr + k0 + bc];
            }
            *(int4*)&Bsh[row][bc] = hv;
            *(int4*)&Bsl[row][bc] = lv;
        }
        __syncthreads();
        #pragma unroll
        for (int ks = 0; ks < 2; ks++){
            int kk = ks*32 + (lane >> 4) * 8;
            bf16x8 ah[2], alo[2], bh[2], blo[2];
            #pragma unroll
            for (int i=0;i<2;i++){
                ah[i]  = *(const bf16x8*)&Ash[wm + i*16 + (lane&15)][kk];
                alo[i] = *(const bf16x8*)&Asl[wm + i*16 + (lane&15)][kk];
                bh[i]  = *(const bf16x8*)&Bsh[wn + i*16 + (lane&15)][kk];
                blo[i] = *(const bf16x8*)&Bsl[wn + i*16 + (lane&15)][kk];
            }
            #pragma unroll
            for (int i=0;i<2;i++)
              #pragma unroll
              for (int j=0;j<2;j++){
                  acc[i][j] = __builtin_amdgcn_mfma_f32_16x16x32_bf16(ah[i],  bh[j],  acc[i][j], 0,0,0);
                  acc[i][j] = __builtin_amdgcn_mfma_f32_16x16x32_bf16(alo[i], bh[j],  acc[i][j], 0,0,0);
                  acc[i][j] = __builtin_amdgcn_mfma_f32_16x16x32_bf16(ah[i],  blo[j], acc[i][j], 0,0,0);
              }
        }
        __syncthreads();
    }
    // epilogue: C row = (lane>>4)*4 + r, col = lane&15 within each 16x16 tile
    #pragma unroll
    for (int i=0;i<2;i++){
        int rbase = m0 + wm + i*16 + (lane>>4)*4;
        #pragma unroll
        for (int j=0;j<2;j++){
            int col = n0 + wn + j*16 + (lane&15);
            if (col >= Nr) continue;
            float bv = bias ? bias[col] : 0.f;
            #pragma unroll
            for (int r=0;r<4;r++){
                int row = rbase + r;
                if (row < Mr){
                    float v = acc[i][j][r] + bv;
                    if (relu) v = v > 0.f ? v : 0.f;
                    C[(size_t)row*Nr + col] = v;
                }
            }
        }
    }
}

// ---------------- attention logits ----------------
__global__ __launch_bounds__(256) void al_kernel(const float* __restrict__ xp,
        const float* __restrict__ a_src, const float* __restrict__ a_dst,
        float* __restrict__ als, float* __restrict__ ald, int N, int H, int C)
{
    int n = blockIdx.x;
    int t = threadIdx.x;
    __shared__ float rs[4], rd[4];
    for (int h=0;h<H;h++){
        float ps=0.f, pd=0.f;
        for (int c=t;c<C;c+=256){
            float v = xp[(size_t)n*H*C + (size_t)h*C + c];
            ps += v * a_src[h*C+c];
            pd += v * a_dst[h*C+c];
        }
        #pragma unroll
        for (int off=32; off; off>>=1){
            ps += __shfl_down(ps, off);
            pd += __shfl_down(pd, off);
        }
        if ((t & 63) == 0){ rs[t>>6]=ps; rd[t>>6]=pd; }
        __syncthreads();
        if (t==0){
            als[n*H+h] = rs[0]+rs[1]+rs[2]+rs[3];
            ald[n*H+h] = rd[0]+rd[1]+rd[2]+rd[3];
        }
        __syncthreads();
    }
}

// ---------------- GAT aggregation per dst node ----------------
template<int H, int C>
__global__ __launch_bounds__(256) void gat_agg(const float* __restrict__ xp,
        const float* __restrict__ als, const float* __restrict__ ald,
        const int* __restrict__ rowptr, const int* __restrict__ col,
        const float* __restrict__ bias, float* __restrict__ out, int N)
{
    constexpr int W  = H*C;
    constexpr int PC = W/256;
    constexpr int CH = 128;
    int n = blockIdx.x;
    int t = threadIdx.x;
    int beg = rowptr[n], end = rowptr[n+1];
    int deg = end - beg;
    __shared__ float red[4];
    __shared__ float m_sh[H], den_sh[H];
    __shared__ int   sidx[CH];
    __shared__ float salpha[CH*H];

    float aldn[H];
    #pragma unroll
    for (int h=0;h<H;h++) aldn[h] = ald[n*H+h];

    for (int h=0;h<H;h++){
        float mx = -1e30f;
        for (int i=t;i<deg;i+=256){
            int s = col[beg+i];
            float e = als[s*H+h] + aldn[h];
            e = e>0.f ? e : 0.2f*e;
            mx = fmaxf(mx, e);
        }
        #pragma unroll
        for (int off=32; off; off>>=1) mx = fmaxf(mx, __shfl_down(mx,off));
        if ((t&63)==0) red[t>>6]=mx;
        __syncthreads();
        if (t==0) m_sh[h] = fmaxf(fmaxf(red[0],red[1]), fmaxf(red[2],red[3]));
        __syncthreads();
        float m = m_sh[h];
        float sm = 0.f;
        for (int i=t;i<deg;i+=256){
            int s = col[beg+i];
            float e = als[s*H+h] + aldn[h];
            e = e>0.f ? e : 0.2f*e;
            sm += expf(e - m);
        }
        #pragma unroll
        for (int off=32; off; off>>=1) sm += __shfl_down(sm,off);
        if ((t&63)==0) red[t>>6]=sm;
        __syncthreads();
        if (t==0) den_sh[h] = red[0]+red[1]+red[2]+red[3];
        __syncthreads();
    }

    float acc[PC];
    #pragma unroll
    for (int j=0;j<PC;j++) acc[j]=0.f;
    float invden[H], msh[H];
    #pragma unroll
    for (int h=0;h<H;h++){ invden[h] = 1.f/(den_sh[h]+1e-16f); msh[h]=m_sh[h]; }

    for (int c0=0;c0<deg;c0+=CH){
        int cl = min(CH, deg-c0);
        __syncthreads();
        if (t < cl){
            int s = col[beg+c0+t];
            sidx[t] = s;
            #pragma unroll
            for (int h=0;h<H;h++){
                float e = als[s*H+h] + aldn[h];
                e = e>0.f ? e : 0.2f*e;
                salpha[t*H+h] = expf(e - msh[h]) * invden[h];
            }
        }
        __syncthreads();
        for (int i=0;i<cl;i++){
            int s = sidx[i];
            const float* row = xp + (size_t)s*W;
            #pragma unroll
            for (int j=0;j<PC;j++){
                int cidx = t + j*256;
                acc[j] += salpha[i*H + (cidx/C)] * row[cidx];
            }
        }
    }
    #pragma unroll
    for (int j=0;j<PC;j++){
        int cidx = t + j*256;
        float v = acc[j] + bias[cidx];
        out[(size_t)n*W + cidx] = v>0.f ? v : 0.f;
    }
}

extern "C" void kernel_launch(void* const* d_in, const int* in_sizes, int n_in,
                              void* d_out, int out_size, void* d_ws, size_t ws_size,
                              hipStream_t stream)
{
    const float* x_m  = (const float*)d_in[0];
    const float* x_d  = (const float*)d_in[1];
    const int*   eix  = (const int*)d_in[2];
    const int*   eiy  = (const int*)d_in[3];
    const float* Wx1  = (const float*)d_in[4];
    const float* ax1s = (const float*)d_in[5];
    const float* ax1d = (const float*)d_in[6];
    const float* bx1  = (const float*)d_in[7];
    const float* Wx2  = (const float*)d_in[8];
    const float* ax2s = (const float*)d_in[9];
    const float* ax2d = (const float*)d_in[10];
    const float* bx2  = (const float*)d_in[11];
    const float* Wy1  = (const float*)d_in[12];
    const float* ay1s = (const float*)d_in[13];
    const float* ay1d = (const float*)d_in[14];
    const float* by1  = (const float*)d_in[15];
    const float* Wy2  = (const float*)d_in[16];
    const float* ay2s = (const float*)d_in[17];
    const float* ay2d = (const float*)d_in[18];
    const float* by2  = (const float*)d_in[19];
    const float* lwx1 = (const float*)d_in[20];
    const float* lbx1 = (const float*)d_in[21];
    const float* lwx2 = (const float*)d_in[22];
    const float* lbx2 = (const float*)d_in[23];
    const float* lwx3 = (const float*)d_in[24];
    const float* lbx3 = (const float*)d_in[25];
    const float* lwy1 = (const float*)d_in[26];
    const float* lby1 = (const float*)d_in[27];
    const float* lwy2 = (const float*)d_in[28];
    const float* lby2 = (const float*)d_in[29];
    const float* lwy3 = (const float*)d_in[30];
    const float* lby3 = (const float*)d_in[31];

    const int N = NODES, E = EDGES;
    char* ws = (char*)d_ws;
    size_t off = 0;
    auto alloc = [&](size_t bytes)->char*{
        size_t a = (off + 255) & ~(size_t)255;
        off = a + bytes;
        return ws + a;
    };
    int* rowptr   = (int*)alloc((size_t)(N+1)*sizeof(int));
    int* cursor   = (int*)alloc((size_t)N*sizeof(int));
    int* counts   = (int*)alloc((size_t)N*sizeof(int));
    int* colidx   = (int*)alloc((size_t)E*sizeof(int));
    float* xp     = (float*)alloc((size_t)N*512*sizeof(float));
    float* bufA   = (float*)alloc((size_t)N*512*sizeof(float));
    float* bufB   = (float*)alloc((size_t)N*256*sizeof(float));
    float* als    = (float*)alloc((size_t)N*2*sizeof(float));
    float* aldv   = (float*)alloc((size_t)N*2*sizeof(float));
    float* xf     = (float*)alloc((size_t)N*64*sizeof(float));
    float* yf     = (float*)alloc((size_t)N*64*sizeof(float));
    short* Bth    = (short*)alloc((size_t)512*512*sizeof(short));
    short* Btl    = (short*)alloc((size_t)512*512*sizeof(short));
    short* Yh     = (short*)alloc((size_t)N*64*sizeof(short));
    short* Yl     = (short*)alloc((size_t)N*64*sizeof(short));

    auto gemm = [&](const float* A, const float* W, float* C, const float* bias,
                    int Kr, int Nr, int relu)
    {
        splitT<<<dim3(Nr/32, Kr/32), dim3(32,8), 0, stream>>>(W, Bth, Btl, Kr, Nr);
        gemm_split<<<dim3((Nr+63)/64, (N+63)/64), 256, 0, stream>>>(
            A, Bth, Btl, C, bias, N, Nr, Kr, relu);
    };

    auto run_graph = [&](const float* xin, const int* ei,
                         const float* W1, const float* a1s, const float* a1d, const float* b1,
                         const float* W2, const float* a2s, const float* a2d, const float* b2,
                         const float* lw1, const float* lb1, const float* lw2, const float* lb2,
                         const float* lw3, const float* lb3, float* outv)
    {
        const int* srcp = ei;
        const int* dstp = ei + E;
        hipMemsetAsync(counts, 0, (size_t)N*sizeof(int), stream);
        count_kernel<<<(E+255)/256, 256, 0, stream>>>(dstp, E, counts);
        scan_kernel<<<1, 1024, 0, stream>>>(counts, rowptr, N);
        hipMemcpyAsync(cursor, rowptr, (size_t)N*sizeof(int), hipMemcpyDeviceToDevice, stream);
        fill_kernel<<<(E+255)/256, 256, 0, stream>>>(srcp, dstp, E, cursor, colidx);
        // layer 1: H=2, C=256 (in 256 -> out 512)
        gemm(xin, W1, xp, nullptr, 256, 512, 0);
        al_kernel<<<N, 256, 0, stream>>>(xp, a1s, a1d, als, aldv, N, 2, 256);
        gat_agg<2,256><<<N, 256, 0, stream>>>(xp, als, aldv, rowptr, colidx, b1, bufA, N);
        // layer 2: H=1, C=256 (in 512 -> out 256)
        gemm(bufA, W2, xp, nullptr, 512, 256, 0);
        al_kernel<<<N, 256, 0, stream>>>(xp, a2s, a2d, als, aldv, N, 1, 256);
        gat_agg<1,256><<<N, 256, 0, stream>>>(xp, als, aldv, rowptr, colidx, b2, bufB, N);
        // MLP head: 256 -> 256 -> 128 -> 64, all relu
        gemm(bufB, lw1, bufA, lb1, 256, 256, 1);
        gemm(bufA, lw2, xp,   lb2, 256, 128, 1);
        gemm(xp,   lw3, outv, lb3, 128, 64,  1);
    };

    run_graph(x_m, eix, Wx1, ax1s, ax1d, bx1, Wx2, ax2s, ax2d, bx2,
              lwx1, lbx1, lwx2, lbx2, lwx3, lbx3, xf);
    run_graph(x_d, eiy, Wy1, ay1s, ay1d, by1, Wy2, ay2s, ay2d, by2,
              lwy1, lby1, lwy2, lby2, lwy3, lby3, yf);

    // final: C[M,D] = X @ Y^T via split MFMA (Y already in [N,K] layout)
    split_rows<<<(N*64/4 + 255)/256, 256, 0, stream>>>(yf, Yh, Yl, N*64);
    gemm_split<<<dim3((N+63)/64, (N+63)/64), 256, 0, stream>>>(
        xf, Yh, Yl, (float*)d_out, nullptr, N, N, 64, 0);
}

// Round 4
// 1148.321 us; speedup vs baseline: 1.1927x; 1.0959x over previous
//
#include <hip/hip_runtime.h>
#include <cstddef>
#include <cstdint>

#define NODES 10000
#define EDGES 320000

typedef __attribute__((ext_vector_type(8))) short bf16x8;
typedef __attribute__((ext_vector_type(4))) float f32x4;

__device__ inline short bf16rn(float x){
    union { float f; unsigned u; } v; v.f = x;
    unsigned r = (v.u + 0x7FFFu + ((v.u >> 16) & 1u)) >> 16;
    return (short)r;
}
__device__ inline float bf16tof(short h){
    union { float f; unsigned u; } v; v.u = ((unsigned)(unsigned short)h) << 16;
    return v.f;
}

// ---------------- CSR build over BOTH graphs stacked (2N nodes, 2E edges) ----------------
__global__ void count2_kernel(const int* __restrict__ ex, const int* __restrict__ ey,
                              int* __restrict__ counts){
    int e = blockIdx.x*256 + threadIdx.x;
    if (e < 2*EDGES){
        int d = (e < EDGES) ? ex[EDGES + e] : (ey[e] + NODES);  // ey[EDGES + (e-EDGES)] == ey[e]
        atomicAdd(&counts[d], 1);
    }
}

__global__ __launch_bounds__(1024) void scan_kernel(const int* __restrict__ counts,
                                                    int* __restrict__ rowptr, int N){
    __shared__ int part[1024];
    int t = threadIdx.x;
    int chunk = (N + 1023) / 1024;
    int b0 = t * chunk;
    int s = 0;
    for (int i=0;i<chunk;i++){ int idx=b0+i; if (idx<N) s += counts[idx]; }
    part[t] = s;
    __syncthreads();
    for (int off=1; off<1024; off<<=1){
        int v = (t>=off) ? part[t-off] : 0;
        __syncthreads();
        part[t] += v;
        __syncthreads();
    }
    int excl = (t==0) ? 0 : part[t-1];
    for (int i=0;i<chunk;i++){
        int idx=b0+i;
        if (idx<N){ rowptr[idx]=excl; excl += counts[idx]; }
    }
    if (t==1023) rowptr[N] = part[1023];
}

__global__ void fill2_kernel(const int* __restrict__ ex, const int* __restrict__ ey,
                             int* __restrict__ cursor, int* __restrict__ col){
    int e = blockIdx.x*256 + threadIdx.x;
    if (e < 2*EDGES){
        int s, d;
        if (e < EDGES){ s = ex[e]; d = ex[EDGES+e]; }
        else          { s = ey[e-EDGES] + NODES; d = ey[e] + NODES; }
        int p = atomicAdd(&cursor[d], 1);
        col[p] = s;
    }
}

// ---------------- w~ precompute: wt[k,h] = sum_c W[k, h*256+c] * a[h*256+c] ----------------
struct WtJob { const float* W; const float* a; float* out; int K; int H; int h; };
struct WtJobs { WtJob j[12]; };
__global__ __launch_bounds__(256) void wtilde_kernel(WtJobs js){
    WtJob jb = js.j[blockIdx.x];
    const int C = 256;
    for (int k = threadIdx.x; k < jb.K; k += 256){
        const float* wr = jb.W + (size_t)k*(jb.H*C) + jb.h*C;
        const float* ar = jb.a + jb.h*C;
        float s = 0.f;
        for (int c=0;c<C;c++) s += wr[c]*ar[c];
        jb.out[k*jb.H + jb.h] = s;
    }
}

// ---------------- weight transpose+split batch: B[K,N] -> [N,K] bf16 hi/lo ----------------
struct StJob { const float* B; short* th; short* tl; int K; int N; };
struct StJobs { StJob j[10]; };
__global__ __launch_bounds__(256) void splitT_batch(StJobs js){
    StJob jb = js.j[blockIdx.z];
    int n0 = blockIdx.x*32, k0 = blockIdx.y*32;
    if (n0 >= jb.N || k0 >= jb.K) return;
    __shared__ float tile[32][33];
    int tx = threadIdx.x, ty = threadIdx.y;
    #pragma unroll
    for (int r=0;r<4;r++){ int k = ty + r*8; tile[k][tx] = jb.B[(size_t)(k0+k)*jb.N + n0 + tx]; }
    __syncthreads();
    #pragma unroll
    for (int r=0;r<4;r++){
        int n = ty + r*8;
        float v = tile[tx][n];
        short h = bf16rn(v);
        jb.th[(size_t)(n0+n)*jb.K + k0 + tx] = h;
        jb.tl[(size_t)(n0+n)*jb.K + k0 + tx] = bf16rn(v - bf16tof(h));
    }
}

// ---------------- split stacked inputs x_m|x_d -> bf16 hi/lo ----------------
__global__ void split_in_kernel(const float* __restrict__ x0, const float* __restrict__ x1,
                                short* __restrict__ h, short* __restrict__ l){
    int i = (blockIdx.x*256 + threadIdx.x)*4;
    const int HALF = NODES*256;
    if (i >= 2*HALF) return;
    const float* src = (i < HALF) ? (x0 + i) : (x1 + (i - HALF));
    float4 v = *(const float4*)src;
    short h0=bf16rn(v.x), h1=bf16rn(v.y), h2=bf16rn(v.z), h3=bf16rn(v.w);
    short4 hv; hv.x=h0; hv.y=h1; hv.z=h2; hv.w=h3;
    short4 lv; lv.x=bf16rn(v.x-bf16tof(h0)); lv.y=bf16rn(v.y-bf16tof(h1));
    lv.z=bf16rn(v.z-bf16tof(h2)); lv.w=bf16rn(v.w-bf16tof(h3));
    *(short4*)&h[i] = hv;
    *(short4*)&l[i] = lv;
}

// ---------------- 3xBF16-split MFMA GEMM, pre-split operands, z-batched ----------------
// C[M,N] = A[M,K] @ Bt[N,K]^T ; tile 96x64xBK64; outputs fp32 C and/or bf16 hi/lo.
struct GemmJob {
    const short* Ah; const short* Al; const short* Bh; const short* Bl;
    float* C; short* Ch; short* Cl; const float* bias;
};
__global__ __launch_bounds__(256) void gemm_ps(GemmJob j0, GemmJob j1,
        int Mr, int Nr, int Kr, int relu)
{
    GemmJob j = (blockIdx.z == 0) ? j0 : j1;
    __shared__ short Ash[96][88], Asl[96][88], Bsh[64][88], Bsl[64][88];
    int t = threadIdx.x;
    int lane = t & 63, wave = t >> 6;
    int wm = (wave >> 1) * 48, wn = (wave & 1) * 32;
    int m0 = blockIdx.y * 96, n0 = blockIdx.x * 64;

    f32x4 acc[3][2];
    #pragma unroll
    for (int i=0;i<3;i++)
      #pragma unroll
      for (int jj=0;jj<2;jj++)
        #pragma unroll
        for (int r=0;r<4;r++) acc[i][jj][r] = 0.f;

    int arow = t >> 3;          // 0..31
    int ablk = (t & 7) * 8;     // 0..56 shorts

    for (int k0 = 0; k0 < Kr; k0 += 64){
        #pragma unroll
        for (int rep=0; rep<3; rep++){
            int row = arow + rep*32;
            int gr = m0 + row; gr = gr < Mr ? gr : Mr-1;
            size_t off = (size_t)gr*Kr + k0 + ablk;
            *(int4*)&Ash[row][ablk] = *(const int4*)&j.Ah[off];
            *(int4*)&Asl[row][ablk] = *(const int4*)&j.Al[off];
        }
        #pragma unroll
        for (int rep=0; rep<2; rep++){
            int row = arow + rep*32;    // 0..63
            int gn = n0 + row; gn = gn < Nr ? gn : Nr-1;
            size_t off = (size_t)gn*Kr + k0 + ablk;
            *(int4*)&Bsh[row][ablk] = *(const int4*)&j.Bh[off];
            *(int4*)&Bsl[row][ablk] = *(const int4*)&j.Bl[off];
        }
        __syncthreads();
        #pragma unroll
        for (int ks=0; ks<2; ks++){
            int kk = ks*32 + (lane>>4)*8;
            bf16x8 bh[2], bl[2];
            #pragma unroll
            for (int jj=0;jj<2;jj++){
                bh[jj] = *(const bf16x8*)&Bsh[wn + jj*16 + (lane&15)][kk];
                bl[jj] = *(const bf16x8*)&Bsl[wn + jj*16 + (lane&15)][kk];
            }
            #pragma unroll
            for (int i=0;i<3;i++){
                bf16x8 ah = *(const bf16x8*)&Ash[wm + i*16 + (lane&15)][kk];
                bf16x8 al = *(const bf16x8*)&Asl[wm + i*16 + (lane&15)][kk];
                #pragma unroll
                for (int jj=0;jj<2;jj++){
                    acc[i][jj] = __builtin_amdgcn_mfma_f32_16x16x32_bf16(ah, bh[jj], acc[i][jj], 0,0,0);
                    acc[i][jj] = __builtin_amdgcn_mfma_f32_16x16x32_bf16(al, bh[jj], acc[i][jj], 0,0,0);
                    acc[i][jj] = __builtin_amdgcn_mfma_f32_16x16x32_bf16(ah, bl[jj], acc[i][jj], 0,0,0);
                }
            }
        }
        __syncthreads();
    }
    #pragma unroll
    for (int i=0;i<3;i++){
        int rbase = m0 + wm + i*16 + ((lane>>4)<<2);
        #pragma unroll
        for (int jj=0;jj<2;jj++){
            int colg = n0 + wn + jj*16 + (lane&15);
            if (colg >= Nr) continue;
            float bv = j.bias ? j.bias[colg] : 0.f;
            #pragma unroll
            for (int r=0;r<4;r++){
                int rg = rbase + r;
                if (rg < Mr){
                    float v = acc[i][jj][r] + bv;
                    if (relu) v = v > 0.f ? v : 0.f;
                    if (j.C) j.C[(size_t)rg*Nr + colg] = v;
                    if (j.Ch){
                        short hh = bf16rn(v);
                        j.Ch[(size_t)rg*Nr + colg] = hh;
                        j.Cl[(size_t)rg*Nr + colg] = bf16rn(v - bf16tof(hh));
                    }
                }
            }
        }
    }
}

// ---------------- attention logits GEMV: als/ald [2N,H] = A @ wt ----------------
template<int H>
__global__ __launch_bounds__(256) void algemv(const float* __restrict__ A0,
        const float* __restrict__ A1, const float* __restrict__ wtS,
        const float* __restrict__ wtD, int K,
        float* __restrict__ als, float* __restrict__ ald)
{
    int node = blockIdx.x*4 + (threadIdx.x>>6);
    int lane = threadIdx.x & 63;
    if (node >= 2*NODES) return;
    int g = node >= NODES;
    const float* A = g ? (A1 + (size_t)(node-NODES)*K) : (A0 + (size_t)node*K);
    const float* ws = wtS + (size_t)g*K*H;
    const float* wd = wtD + (size_t)g*K*H;
    float ss[H], sd[H];
    #pragma unroll
    for (int h=0;h<H;h++){ ss[h]=0.f; sd[h]=0.f; }
    for (int k=lane; k<K; k+=64){
        float v = A[k];
        #pragma unroll
        for (int h=0;h<H;h++){ ss[h] += v*ws[k*H+h]; sd[h] += v*wd[k*H+h]; }
    }
    #pragma unroll
    for (int off=32; off; off>>=1){
        #pragma unroll
        for (int h=0;h<H;h++){ ss[h] += __shfl_xor(ss[h], off); sd[h] += __shfl_xor(sd[h], off); }
    }
    if (lane==0){
        #pragma unroll
        for (int h=0;h<H;h++){ als[node*H+h]=ss[h]; ald[node*H+h]=sd[h]; }
    }
}

// ---------------- per-edge softmax alpha (wave per dst node) ----------------
template<int H>
__global__ __launch_bounds__(256) void alpha_kernel(const int* __restrict__ rowptr,
        const int* __restrict__ col, const float* __restrict__ als,
        const float* __restrict__ ald, float* __restrict__ alpha)
{
    int node = blockIdx.x*4 + (threadIdx.x>>6);
    int lane = threadIdx.x & 63;
    if (node >= 2*NODES) return;
    int beg = rowptr[node], end = rowptr[node+1];
    #pragma unroll
    for (int h=0; h<H; h++){
        float ad = ald[node*H+h];
        float mx = -1e30f;
        for (int p=beg+lane; p<end; p+=64){
            float e = als[col[p]*H+h] + ad;
            e = e>0.f ? e : 0.2f*e;
            mx = fmaxf(mx, e);
        }
        #pragma unroll
        for (int off=32; off; off>>=1) mx = fmaxf(mx, __shfl_xor(mx, off));
        float sm = 0.f;
        for (int p=beg+lane; p<end; p+=64){
            float e = als[col[p]*H+h] + ad;
            e = e>0.f ? e : 0.2f*e;
            sm += __expf(e - mx);
        }
        #pragma unroll
        for (int off=32; off; off>>=1) sm += __shfl_xor(sm, off);
        float inv = 1.f/(sm + 1e-16f);
        for (int p=beg+lane; p<end; p+=64){
            float e = als[col[p]*H+h] + ad;
            e = e>0.f ? e : 0.2f*e;
            alpha[(size_t)p*H + h] = __expf(e - mx)*inv;
        }
    }
}

// ---------------- aggregation: wave per dst node, gather xp rows ----------------
template<int W, int H>
__global__ __launch_bounds__(256) void agg_ps(const float* __restrict__ xp,
        const float* __restrict__ alpha, const int* __restrict__ rowptr,
        const int* __restrict__ col, const float* __restrict__ bias0,
        const float* __restrict__ bias1, float* __restrict__ out,
        short* __restrict__ outH, short* __restrict__ outL)
{
    int node = blockIdx.x*4 + (threadIdx.x>>6);
    int lane = threadIdx.x & 63;
    if (node >= 2*NODES) return;
    int beg = rowptr[node], end = rowptr[node+1];
    constexpr int NF = W/64;                    // floats per lane: 8 (W=512) or 4 (W=256)
    int lb = lane*NF;
    int hsel = (H==2) ? (lane>>5) : 0;
    float4 a0 = make_float4(0.f,0.f,0.f,0.f);
    float4 a1 = make_float4(0.f,0.f,0.f,0.f);
    for (int p=beg; p<end; p++){
        int s = col[p];
        float av = alpha[(size_t)p*H + hsel];
        const float* row = xp + (size_t)s*W + lb;
        float4 v0 = *(const float4*)row;
        a0.x += av*v0.x; a0.y += av*v0.y; a0.z += av*v0.z; a0.w += av*v0.w;
        if (NF==8){
            float4 v1 = *(const float4*)(row+4);
            a1.x += av*v1.x; a1.y += av*v1.y; a1.z += av*v1.z; a1.w += av*v1.w;
        }
    }
    const float* bs = (node >= NODES) ? bias1 : bias0;
    float4 bv = *(const float4*)&bs[lb];
    float r0 = fmaxf(a0.x+bv.x, 0.f), r1 = fmaxf(a0.y+bv.y, 0.f);
    float r2 = fmaxf(a0.z+bv.z, 0.f), r3 = fmaxf(a0.w+bv.w, 0.f);
    size_t base = (size_t)node*W + lb;
    if (out){ float4 o = make_float4(r0,r1,r2,r3); *(float4*)&out[base] = o; }
    short4 hh, ll;
    hh.x=bf16rn(r0); hh.y=bf16rn(r1); hh.z=bf16rn(r2); hh.w=bf16rn(r3);
    ll.x=bf16rn(r0-bf16tof(hh.x)); ll.y=bf16rn(r1-bf16tof(hh.y));
    ll.z=bf16rn(r2-bf16tof(hh.z)); ll.w=bf16rn(r3-bf16tof(hh.w));
    *(short4*)&outH[base] = hh;
    *(short4*)&outL[base] = ll;
    if (NF==8){
        float4 bw = *(const float4*)&bs[lb+4];
        float s0 = fmaxf(a1.x+bw.x, 0.f), s1 = fmaxf(a1.y+bw.y, 0.f);
        float s2 = fmaxf(a1.z+bw.z, 0.f), s3 = fmaxf(a1.w+bw.w, 0.f);
        if (out){ float4 o = make_float4(s0,s1,s2,s3); *(float4*)&out[base+4] = o; }
        hh.x=bf16rn(s0); hh.y=bf16rn(s1); hh.z=bf16rn(s2); hh.w=bf16rn(s3);
        ll.x=bf16rn(s0-bf16tof(hh.x)); ll.y=bf16rn(s1-bf16tof(hh.y));
        ll.z=bf16rn(s2-bf16tof(hh.z)); ll.w=bf16rn(s3-bf16tof(hh.w));
        *(short4*)&outH[base+4] = hh;
        *(short4*)&outL[base+4] = ll;
    }
}

extern "C" void kernel_launch(void* const* d_in, const int* in_sizes, int n_in,
                              void* d_out, int out_size, void* d_ws, size_t ws_size,
                              hipStream_t stream)
{
    const float* x_m  = (const float*)d_in[0];
    const float* x_d  = (const float*)d_in[1];
    const int*   eix  = (const int*)d_in[2];
    const int*   eiy  = (const int*)d_in[3];
    const float* Wx1  = (const float*)d_in[4];
    const float* ax1s = (const float*)d_in[5];
    const float* ax1d = (const float*)d_in[6];
    const float* bx1  = (const float*)d_in[7];
    const float* Wx2  = (const float*)d_in[8];
    const float* ax2s = (const float*)d_in[9];
    const float* ax2d = (const float*)d_in[10];
    const float* bx2  = (const float*)d_in[11];
    const float* Wy1  = (const float*)d_in[12];
    const float* ay1s = (const float*)d_in[13];
    const float* ay1d = (const float*)d_in[14];
    const float* by1  = (const float*)d_in[15];
    const float* Wy2  = (const float*)d_in[16];
    const float* ay2s = (const float*)d_in[17];
    const float* ay2d = (const float*)d_in[18];
    const float* by2  = (const float*)d_in[19];
    const float* lwx1 = (const float*)d_in[20];
    const float* lbx1 = (const float*)d_in[21];
    const float* lwx2 = (const float*)d_in[22];
    const float* lbx2 = (const float*)d_in[23];
    const float* lwx3 = (const float*)d_in[24];
    const float* lbx3 = (const float*)d_in[25];
    const float* lwy1 = (const float*)d_in[26];
    const float* lby1 = (const float*)d_in[27];
    const float* lwy2 = (const float*)d_in[28];
    const float* lby2 = (const float*)d_in[29];
    const float* lwy3 = (const float*)d_in[30];
    const float* lby3 = (const float*)d_in[31];

    const int N = NODES, E = EDGES, N2 = 2*NODES;
    char* ws = (char*)d_ws;
    size_t off = 0;
    auto alloc = [&](size_t bytes)->char*{
        size_t a = (off + 255) & ~(size_t)255;
        off = a + bytes;
        return ws + a;
    };
    int* rowptr = (int*)alloc((size_t)(N2+1)*4);
    int* cursor = (int*)alloc((size_t)N2*4);
    int* counts = (int*)alloc((size_t)N2*4);
    int* colidx = (int*)alloc((size_t)2*E*4);
    float* alphaA = (float*)alloc((size_t)2*E*2*4);
    short* xinh = (short*)alloc((size_t)N2*256*2);
    short* xinl = (short*)alloc((size_t)N2*256*2);
    float* xp   = (float*)alloc((size_t)N2*512*4);
    float* als1 = (float*)alloc((size_t)N2*2*4);
    float* ald1 = (float*)alloc((size_t)N2*2*4);
    float* bufA = (float*)alloc((size_t)N2*512*4);
    short* bufAh = (short*)alloc((size_t)N2*512*2);
    short* bufAl = (short*)alloc((size_t)N2*512*2);
    float* xp2  = (float*)alloc((size_t)N2*256*4);
    float* als2 = (float*)alloc((size_t)N2*4);
    float* ald2 = (float*)alloc((size_t)N2*4);
    short* bufBh = (short*)alloc((size_t)N2*256*2);
    short* bufBl = (short*)alloc((size_t)N2*256*2);
    short* m1h = (short*)alloc((size_t)N2*256*2);
    short* m1l = (short*)alloc((size_t)N2*256*2);
    short* m2h = (short*)alloc((size_t)N2*128*2);
    short* m2l = (short*)alloc((size_t)N2*128*2);
    short* m3h = (short*)alloc((size_t)N2*64*2);
    short* m3l = (short*)alloc((size_t)N2*64*2);
    float* wt1s = (float*)alloc((size_t)2*256*2*4);
    float* wt1d = (float*)alloc((size_t)2*256*2*4);
    float* wt2s = (float*)alloc((size_t)2*512*4);
    float* wt2d = (float*)alloc((size_t)2*512*4);
    auto sal = [&](size_t n)->short*{ return (short*)alloc(n*2); };
    short* w1h0 = sal(512*256), *w1l0 = sal(512*256), *w1h1 = sal(512*256), *w1l1 = sal(512*256);
    short* w2h0 = sal(256*512), *w2l0 = sal(256*512), *w2h1 = sal(256*512), *w2l1 = sal(256*512);
    short* l1h0 = sal(256*256), *l1l0 = sal(256*256), *l1h1 = sal(256*256), *l1l1 = sal(256*256);
    short* l2h0 = sal(128*256), *l2l0 = sal(128*256), *l2h1 = sal(128*256), *l2l1 = sal(128*256);
    short* l3h0 = sal(64*128),  *l3l0 = sal(64*128),  *l3h1 = sal(64*128),  *l3l1 = sal(64*128);

    // --- CSR (both graphs) ---
    hipMemsetAsync(counts, 0, (size_t)N2*4, stream);
    count2_kernel<<<(2*E+255)/256, 256, 0, stream>>>(eix, eiy, counts);
    scan_kernel<<<1, 1024, 0, stream>>>(counts, rowptr, N2);
    hipMemcpyAsync(cursor, rowptr, (size_t)N2*4, hipMemcpyDeviceToDevice, stream);
    fill2_kernel<<<(2*E+255)/256, 256, 0, stream>>>(eix, eiy, cursor, colidx);

    // --- w~ ---
    WtJobs wj;
    wj.j[0] = {Wx1, ax1s, wt1s,         256, 2, 0};
    wj.j[1] = {Wx1, ax1s, wt1s,         256, 2, 1};
    wj.j[2] = {Wx1, ax1d, wt1d,         256, 2, 0};
    wj.j[3] = {Wx1, ax1d, wt1d,         256, 2, 1};
    wj.j[4] = {Wy1, ay1s, wt1s+256*2,   256, 2, 0};
    wj.j[5] = {Wy1, ay1s, wt1s+256*2,   256, 2, 1};
    wj.j[6] = {Wy1, ay1d, wt1d+256*2,   256, 2, 0};
    wj.j[7] = {Wy1, ay1d, wt1d+256*2,   256, 2, 1};
    wj.j[8] = {Wx2, ax2s, wt2s,         512, 1, 0};
    wj.j[9] = {Wx2, ax2d, wt2d,         512, 1, 0};
    wj.j[10]= {Wy2, ay2s, wt2s+512,     512, 1, 0};
    wj.j[11]= {Wy2, ay2d, wt2d+512,     512, 1, 0};
    wtilde_kernel<<<12, 256, 0, stream>>>(wj);

    // --- weight transpose+split ---
    StJobs sj;
    sj.j[0] = {Wx1,  w1h0, w1l0, 256, 512};
    sj.j[1] = {Wy1,  w1h1, w1l1, 256, 512};
    sj.j[2] = {Wx2,  w2h0, w2l0, 512, 256};
    sj.j[3] = {Wy2,  w2h1, w2l1, 512, 256};
    sj.j[4] = {lwx1, l1h0, l1l0, 256, 256};
    sj.j[5] = {lwy1, l1h1, l1l1, 256, 256};
    sj.j[6] = {lwx2, l2h0, l2l0, 256, 128};
    sj.j[7] = {lwy2, l2h1, l2l1, 256, 128};
    sj.j[8] = {lwx3, l3h0, l3l0, 128, 64};
    sj.j[9] = {lwy3, l3h1, l3l1, 128, 64};
    splitT_batch<<<dim3(16,16,10), dim3(32,8), 0, stream>>>(sj);

    // --- split inputs ---
    split_in_kernel<<<(N2*256/4 + 255)/256, 256, 0, stream>>>(x_m, x_d, xinh, xinl);

    GemmJob jz = {nullptr,nullptr,nullptr,nullptr,nullptr,nullptr,nullptr,nullptr};

    // --- layer 1 GEMM: [2N,256] @ [512,256]^T -> xp [2N,512] ---
    {
        GemmJob a = {xinh, xinl, w1h0, w1l0, xp, nullptr, nullptr, nullptr};
        GemmJob b = {xinh + (size_t)N*256, xinl + (size_t)N*256, w1h1, w1l1,
                     xp + (size_t)N*512, nullptr, nullptr, nullptr};
        gemm_ps<<<dim3(8, (N+95)/96, 2), 256, 0, stream>>>(a, b, N, 512, 256, 0);
    }
    algemv<2><<<(N2+3)/4, 256, 0, stream>>>(x_m, x_d, wt1s, wt1d, 256, als1, ald1);
    alpha_kernel<2><<<(N2+3)/4, 256, 0, stream>>>(rowptr, colidx, als1, ald1, alphaA);
    agg_ps<512,2><<<(N2+3)/4, 256, 0, stream>>>(xp, alphaA, rowptr, colidx,
                                                bx1, by1, bufA, bufAh, bufAl);
    // --- layer 2 GEMM: [2N,512] @ [256,512]^T -> xp2 [2N,256] ---
    {
        GemmJob a = {bufAh, bufAl, w2h0, w2l0, xp2, nullptr, nullptr, nullptr};
        GemmJob b = {bufAh + (size_t)N*512, bufAl + (size_t)N*512, w2h1, w2l1,
                     xp2 + (size_t)N*256, nullptr, nullptr, nullptr};
        gemm_ps<<<dim3(4, (N+95)/96, 2), 256, 0, stream>>>(a, b, N, 256, 512, 0);
    }
    algemv<1><<<(N2+3)/4, 256, 0, stream>>>(bufA, bufA + (size_t)N*512, wt2s, wt2d, 512, als2, ald2);
    alpha_kernel<1><<<(N2+3)/4, 256, 0, stream>>>(rowptr, colidx, als2, ald2, alphaA);
    agg_ps<256,1><<<(N2+3)/4, 256, 0, stream>>>(xp2, alphaA, rowptr, colidx,
                                                bx2, by2, nullptr, bufBh, bufBl);
    // --- MLP head ---
    {
        GemmJob a = {bufBh, bufBl, l1h0, l1l0, nullptr, m1h, m1l, lbx1};
        GemmJob b = {bufBh + (size_t)N*256, bufBl + (size_t)N*256, l1h1, l1l1,
                     nullptr, m1h + (size_t)N*256, m1l + (size_t)N*256, lby1};
        gemm_ps<<<dim3(4, (N+95)/96, 2), 256, 0, stream>>>(a, b, N, 256, 256, 1);
    }
    {
        GemmJob a = {m1h, m1l, l2h0, l2l0, nullptr, m2h, m2l, lbx2};
        GemmJob b = {m1h + (size_t)N*256, m1l + (size_t)N*256, l2h1, l2l1,
                     nullptr, m2h + (size_t)N*128, m2l + (size_t)N*128, lby2};
        gemm_ps<<<dim3(2, (N+95)/96, 2), 256, 0, stream>>>(a, b, N, 128, 256, 1);
    }
    {
        GemmJob a = {m2h, m2l, l3h0, l3l0, nullptr, m3h, m3l, lbx3};
        GemmJob b = {m2h + (size_t)N*128, m2l + (size_t)N*128, l3h1, l3l1,
                     nullptr, m3h + (size_t)N*64, m3l + (size_t)N*64, lby3};
        gemm_ps<<<dim3(1, (N+95)/96, 2), 256, 0, stream>>>(a, b, N, 64, 128, 1);
    }
    // --- final: d_out[M,D] = X @ Y^T ---
    {
        GemmJob a = {m3h, m3l, m3h + (size_t)N*64, m3l + (size_t)N*64,
                     (float*)d_out, nullptr, nullptr, nullptr};
        gemm_ps<<<dim3((N+63)/64, (N+95)/96, 1), 256, 0, stream>>>(a, jz, N, N, 64, 0);
    }
}

// Round 6
// 1047.152 us; speedup vs baseline: 1.3079x; 1.0966x over previous
//
#include <hip/hip_runtime.h>
#include <cstddef>
#include <cstdint>

#define NODES 10000
#define EDGES 320000

typedef __attribute__((ext_vector_type(8))) short bf16x8;
typedef __attribute__((ext_vector_type(4))) float f32x4;

__device__ inline short bf16rn(float x){
    union { float f; unsigned u; } v; v.f = x;
    unsigned r = (v.u + 0x7FFFu + ((v.u >> 16) & 1u)) >> 16;
    return (short)r;
}
__device__ inline float bf16tof(short h){
    union { float f; unsigned u; } v; v.u = ((unsigned)(unsigned short)h) << 16;
    return v.f;
}

// ---------------- CSR build over BOTH graphs stacked (2N nodes, 2E edges) ----------------
__global__ void count2_kernel(const int* __restrict__ ex, const int* __restrict__ ey,
                              int* __restrict__ counts){
    int e = blockIdx.x*256 + threadIdx.x;
    if (e < 2*EDGES){
        int d = (e < EDGES) ? ex[EDGES + e] : (ey[e] + NODES);
        atomicAdd(&counts[d], 1);
    }
}

__global__ __launch_bounds__(1024) void scan_kernel(const int* __restrict__ counts,
                                                    int* __restrict__ rowptr, int N){
    __shared__ int part[1024];
    int t = threadIdx.x;
    int chunk = (N + 1023) / 1024;
    int b0 = t * chunk;
    int s = 0;
    for (int i=0;i<chunk;i++){ int idx=b0+i; if (idx<N) s += counts[idx]; }
    part[t] = s;
    __syncthreads();
    for (int off=1; off<1024; off<<=1){
        int v = (t>=off) ? part[t-off] : 0;
        __syncthreads();
        part[t] += v;
        __syncthreads();
    }
    int excl = (t==0) ? 0 : part[t-1];
    for (int i=0;i<chunk;i++){
        int idx=b0+i;
        if (idx<N){ rowptr[idx]=excl; excl += counts[idx]; }
    }
    if (t==1023) rowptr[N] = part[1023];
}

__global__ void fill2_kernel(const int* __restrict__ ex, const int* __restrict__ ey,
                             int* __restrict__ cursor, int* __restrict__ col){
    int e = blockIdx.x*256 + threadIdx.x;
    if (e < 2*EDGES){
        int s, d;
        if (e < EDGES){ s = ex[e]; d = ex[EDGES+e]; }
        else          { s = ey[e-EDGES] + NODES; d = ey[e] + NODES; }
        int p = atomicAdd(&cursor[d], 1);
        col[p] = s;
    }
}

// ---------------- w~ precompute: wt[k,h] = sum_c W[k, h*256+c] * a[h*256+c] ----------------
struct WtJob { const float* W; const float* a; float* out; int K; int H; int h; };
struct WtJobs { WtJob j[12]; };
__global__ __launch_bounds__(256) void wtilde_kernel(WtJobs js){
    WtJob jb = js.j[blockIdx.x];
    const int C = 256;
    for (int k = threadIdx.x; k < jb.K; k += 256){
        const float* wr = jb.W + (size_t)k*(jb.H*C) + jb.h*C;
        const float* ar = jb.a + jb.h*C;
        float s = 0.f;
        for (int c=0;c<C;c++) s += wr[c]*ar[c];
        jb.out[k*jb.H + jb.h] = s;
    }
}

// ---------------- weight transpose+split batch: B[K,N] -> [N,K] bf16 hi/lo ----------------
struct StJob { const float* B; short* th; short* tl; int K; int N; };
struct StJobs { StJob j[10]; };
__global__ __launch_bounds__(256) void splitT_batch(StJobs js){
    StJob jb = js.j[blockIdx.z];
    int n0 = blockIdx.x*32, k0 = blockIdx.y*32;
    if (n0 >= jb.N || k0 >= jb.K) return;
    __shared__ float tile[32][33];
    int tx = threadIdx.x, ty = threadIdx.y;
    #pragma unroll
    for (int r=0;r<4;r++){ int k = ty + r*8; tile[k][tx] = jb.B[(size_t)(k0+k)*jb.N + n0 + tx]; }
    __syncthreads();
    #pragma unroll
    for (int r=0;r<4;r++){
        int n = ty + r*8;
        float v = tile[tx][n];
        short h = bf16rn(v);
        jb.th[(size_t)(n0+n)*jb.K + k0 + tx] = h;
        jb.tl[(size_t)(n0+n)*jb.K + k0 + tx] = bf16rn(v - bf16tof(h));
    }
}

// ---------------- input split (wave per row) + fused layer-1 attention logits ----------------
__global__ __launch_bounds__(256) void split_in2(const float* __restrict__ x0,
        const float* __restrict__ x1, const float* __restrict__ wt1s,
        const float* __restrict__ wt1d, short* __restrict__ hh, short* __restrict__ ll,
        float* __restrict__ als, float* __restrict__ ald)
{
    int node = blockIdx.x*4 + (threadIdx.x>>6);
    int lane = threadIdx.x & 63;
    if (node >= 2*NODES) return;
    int g = node >= NODES;
    const float* X = g ? (x1 + (size_t)(node-NODES)*256) : (x0 + (size_t)node*256);
    const float* ws = wt1s + g*512;   // [256,2]
    const float* wd = wt1d + g*512;
    float4 v = *(const float4*)&X[lane*4];
    short4 hv, lv;
    hv.x=bf16rn(v.x); hv.y=bf16rn(v.y); hv.z=bf16rn(v.z); hv.w=bf16rn(v.w);
    lv.x=bf16rn(v.x-bf16tof(hv.x)); lv.y=bf16rn(v.y-bf16tof(hv.y));
    lv.z=bf16rn(v.z-bf16tof(hv.z)); lv.w=bf16rn(v.w-bf16tof(hv.w));
    size_t base = (size_t)node*256 + lane*4;
    *(short4*)&hh[base] = hv;
    *(short4*)&ll[base] = lv;
    float s0=0.f,s1=0.f,d0=0.f,d1=0.f;
    float vv[4] = {v.x,v.y,v.z,v.w};
    #pragma unroll
    for (int q=0;q<4;q++){
        int k = lane*4+q;
        s0 += vv[q]*ws[k*2+0]; s1 += vv[q]*ws[k*2+1];
        d0 += vv[q]*wd[k*2+0]; d1 += vv[q]*wd[k*2+1];
    }
    #pragma unroll
    for (int off=32; off; off>>=1){
        s0 += __shfl_xor(s0,off); s1 += __shfl_xor(s1,off);
        d0 += __shfl_xor(d0,off); d1 += __shfl_xor(d1,off);
    }
    if (lane==0){
        als[node*2]=s0; als[node*2+1]=s1;
        ald[node*2]=d0; ald[node*2+1]=d1;
    }
}

// ---------------- 3xBF16-split MFMA GEMM, LDS-staged vectorized epilogue ----------------
struct GemmJob {
    const short* Ah; const short* Al; const short* Bh; const short* Bl;
    float* C; short* Ch; short* Cl; const float* bias;
};
__global__ __launch_bounds__(256) void gemm_ps(GemmJob j0, GemmJob j1,
        int Mr, int Nr, int Kr, int relu)
{
    GemmJob j = (blockIdx.z == 0) ? j0 : j1;
    __shared__ short smem[28160];                         // 56320 B
    short (*Ash)[88] = (short(*)[88])(smem);              // 96x88
    short (*Asl)[88] = (short(*)[88])(smem + 8448);
    short (*Bsh)[88] = (short(*)[88])(smem + 16896);      // 64x88
    short (*Bsl)[88] = (short(*)[88])(smem + 22528);
    int t = threadIdx.x;
    int lane = t & 63, wave = t >> 6;
    int wm = (wave >> 1) * 48, wn = (wave & 1) * 32;
    int m0 = blockIdx.y * 96, n0 = blockIdx.x * 64;

    f32x4 acc[3][2];
    #pragma unroll
    for (int i=0;i<3;i++)
      #pragma unroll
      for (int jj=0;jj<2;jj++)
        #pragma unroll
        for (int r=0;r<4;r++) acc[i][jj][r] = 0.f;

    int arow = t >> 3;          // 0..31
    int ablk = (t & 7) * 8;     // 0..56 shorts

    for (int k0 = 0; k0 < Kr; k0 += 64){
        #pragma unroll
        for (int rep=0; rep<3; rep++){
            int row = arow + rep*32;
            int gr = m0 + row; gr = gr < Mr ? gr : Mr-1;
            size_t off = (size_t)gr*Kr + k0 + ablk;
            *(int4*)&Ash[row][ablk] = *(const int4*)&j.Ah[off];
            *(int4*)&Asl[row][ablk] = *(const int4*)&j.Al[off];
        }
        #pragma unroll
        for (int rep=0; rep<2; rep++){
            int row = arow + rep*32;
            int gn = n0 + row; gn = gn < Nr ? gn : Nr-1;
            size_t off = (size_t)gn*Kr + k0 + ablk;
            *(int4*)&Bsh[row][ablk] = *(const int4*)&j.Bh[off];
            *(int4*)&Bsl[row][ablk] = *(const int4*)&j.Bl[off];
        }
        __syncthreads();
        #pragma unroll
        for (int ks=0; ks<2; ks++){
            int kk = ks*32 + (lane>>4)*8;
            bf16x8 bh[2], bl[2];
            #pragma unroll
            for (int jj=0;jj<2;jj++){
                bh[jj] = *(const bf16x8*)&Bsh[wn + jj*16 + (lane&15)][kk];
                bl[jj] = *(const bf16x8*)&Bsl[wn + jj*16 + (lane&15)][kk];
            }
            #pragma unroll
            for (int i=0;i<3;i++){
                bf16x8 ah = *(const bf16x8*)&Ash[wm + i*16 + (lane&15)][kk];
                bf16x8 al = *(const bf16x8*)&Asl[wm + i*16 + (lane&15)][kk];
                #pragma unroll
                for (int jj=0;jj<2;jj++){
                    acc[i][jj] = __builtin_amdgcn_mfma_f32_16x16x32_bf16(ah, bh[jj], acc[i][jj], 0,0,0);
                    acc[i][jj] = __builtin_amdgcn_mfma_f32_16x16x32_bf16(al, bh[jj], acc[i][jj], 0,0,0);
                    acc[i][jj] = __builtin_amdgcn_mfma_f32_16x16x32_bf16(ah, bl[jj], acc[i][jj], 0,0,0);
                }
            }
        }
        __syncthreads();
    }
    // ---- epilogue: acc -> LDS (fp32) -> coalesced vector stores ----
    float* eplds = (float*)smem;      // 96 x 68 floats = 26112 B
    const int EL = 68;
    #pragma unroll
    for (int i=0;i<3;i++){
        int row = wm + i*16 + ((lane>>4)<<2);
        #pragma unroll
        for (int jj=0;jj<2;jj++){
            int colL = wn + jj*16 + (lane&15);
            #pragma unroll
            for (int r=0;r<4;r++)
                eplds[(row+r)*EL + colL] = acc[i][jj][r];
        }
    }
    __syncthreads();
    int tx = t & 15, ty = t >> 4;
    int colg = n0 + tx*4;
    float4 bv = make_float4(0.f,0.f,0.f,0.f);
    if (j.bias && colg < Nr) bv = *(const float4*)&j.bias[colg];
    #pragma unroll
    for (int rep=0; rep<6; rep++){
        int row = ty + rep*16;
        int rg = m0 + row;
        if (rg >= Mr || colg >= Nr) continue;
        float4 v = *(float4*)&eplds[row*EL + tx*4];
        v.x += bv.x; v.y += bv.y; v.z += bv.z; v.w += bv.w;
        if (relu){
            v.x = fmaxf(v.x,0.f); v.y = fmaxf(v.y,0.f);
            v.z = fmaxf(v.z,0.f); v.w = fmaxf(v.w,0.f);
        }
        if (j.C) *(float4*)&j.C[(size_t)rg*Nr + colg] = v;
        if (j.Ch){
            short4 hv, lv;
            hv.x=bf16rn(v.x); hv.y=bf16rn(v.y); hv.z=bf16rn(v.z); hv.w=bf16rn(v.w);
            lv.x=bf16rn(v.x-bf16tof(hv.x)); lv.y=bf16rn(v.y-bf16tof(hv.y));
            lv.z=bf16rn(v.z-bf16tof(hv.z)); lv.w=bf16rn(v.w-bf16tof(hv.w));
            *(short4*)&j.Ch[(size_t)rg*Nr + colg] = hv;
            *(short4*)&j.Cl[(size_t)rg*Nr + colg] = lv;
        }
    }
}

// ---------------- fused softmax + aggregation: wave per (node, 256-feat half) ----------------
// alpha recomputed inline from als/ald; epilogue writes bf16 hi/lo; optional fused
// next-layer logits partial dot (DOT=1) accumulated via atomicAdd into als2/ald2.
template<int W, int H, int DOT>
__global__ __launch_bounds__(256) void agg_fused(const float* __restrict__ xp,
        const float* __restrict__ als, const float* __restrict__ ald,
        const int* __restrict__ rowptr, const int* __restrict__ col,
        const float* __restrict__ bias0, const float* __restrict__ bias1,
        short* __restrict__ outH, short* __restrict__ outL,
        const float* __restrict__ w2s, const float* __restrict__ w2d,
        float* __restrict__ als2, float* __restrict__ ald2)
{
    constexpr int HALVES = W/256;
    int w = blockIdx.x*4 + (threadIdx.x>>6);
    int lane = threadIdx.x & 63;
    int node = w / HALVES;
    int half = w - node*HALVES;
    if (node >= 2*NODES) return;
    int h = (H==2) ? half : 0;
    int beg = rowptr[node], end = rowptr[node+1];
    float ad = ald[node*H+h];
    float mx = -1e30f;
    for (int p=beg+lane; p<end; p+=64){
        float e = als[col[p]*H+h] + ad;
        e = e>0.f ? e : 0.2f*e;
        mx = fmaxf(mx, e);
    }
    #pragma unroll
    for (int off=32; off; off>>=1) mx = fmaxf(mx, __shfl_xor(mx, off));
    float sm = 0.f;
    for (int p=beg+lane; p<end; p+=64){
        float e = als[col[p]*H+h] + ad;
        e = e>0.f ? e : 0.2f*e;
        sm += __expf(e - mx);
    }
    #pragma unroll
    for (int off=32; off; off>>=1) sm += __shfl_xor(sm, off);
    float inv = 1.f/(sm + 1e-16f);

    int cbase = half*256 + lane*4;
    float4 a = make_float4(0.f,0.f,0.f,0.f);
    for (int p=beg; p<end; p++){
        int s = col[p];
        float e = als[s*H+h] + ad;
        e = e>0.f ? e : 0.2f*e;
        float wv = __expf(e - mx)*inv;
        float4 v = *(const float4*)&xp[(size_t)s*W + cbase];
        a.x += wv*v.x; a.y += wv*v.y; a.z += wv*v.z; a.w += wv*v.w;
    }
    const float* bs = (node >= NODES) ? bias1 : bias0;
    float4 bv = *(const float4*)&bs[cbase];
    float r0 = fmaxf(a.x+bv.x, 0.f), r1 = fmaxf(a.y+bv.y, 0.f);
    float r2 = fmaxf(a.z+bv.z, 0.f), r3 = fmaxf(a.w+bv.w, 0.f);
    size_t base = (size_t)node*W + cbase;
    short4 hv, lv;
    hv.x=bf16rn(r0); hv.y=bf16rn(r1); hv.z=bf16rn(r2); hv.w=bf16rn(r3);
    lv.x=bf16rn(r0-bf16tof(hv.x)); lv.y=bf16rn(r1-bf16tof(hv.y));
    lv.z=bf16rn(r2-bf16tof(hv.z)); lv.w=bf16rn(r3-bf16tof(hv.w));
    *(short4*)&outH[base] = hv;
    *(short4*)&outL[base] = lv;
    if (DOT){
        int g = node >= NODES;
        const float* s2 = w2s + (size_t)g*W;
        const float* d2 = w2d + (size_t)g*W;
        float ss = r0*s2[cbase] + r1*s2[cbase+1] + r2*s2[cbase+2] + r3*s2[cbase+3];
        float dd = r0*d2[cbase] + r1*d2[cbase+1] + r2*d2[cbase+2] + r3*d2[cbase+3];
        #pragma unroll
        for (int off=32; off; off>>=1){
            ss += __shfl_xor(ss, off); dd += __shfl_xor(dd, off);
        }
        if (lane==0){
            atomicAdd(&als2[node], ss);
            atomicAdd(&ald2[node], dd);
        }
    }
}

extern "C" void kernel_launch(void* const* d_in, const int* in_sizes, int n_in,
                              void* d_out, int out_size, void* d_ws, size_t ws_size,
                              hipStream_t stream)
{
    const float* x_m  = (const float*)d_in[0];
    const float* x_d  = (const float*)d_in[1];
    const int*   eix  = (const int*)d_in[2];
    const int*   eiy  = (const int*)d_in[3];
    const float* Wx1  = (const float*)d_in[4];
    const float* ax1s = (const float*)d_in[5];
    const float* ax1d = (const float*)d_in[6];
    const float* bx1  = (const float*)d_in[7];
    const float* Wx2  = (const float*)d_in[8];
    const float* ax2s = (const float*)d_in[9];
    const float* ax2d = (const float*)d_in[10];
    const float* bx2  = (const float*)d_in[11];
    const float* Wy1  = (const float*)d_in[12];
    const float* ay1s = (const float*)d_in[13];
    const float* ay1d = (const float*)d_in[14];
    const float* by1  = (const float*)d_in[15];
    const float* Wy2  = (const float*)d_in[16];
    const float* ay2s = (const float*)d_in[17];
    const float* ay2d = (const float*)d_in[18];
    const float* by2  = (const float*)d_in[19];
    const float* lwx1 = (const float*)d_in[20];
    const float* lbx1 = (const float*)d_in[21];
    const float* lwx2 = (const float*)d_in[22];
    const float* lbx2 = (const float*)d_in[23];
    const float* lwx3 = (const float*)d_in[24];
    const float* lbx3 = (const float*)d_in[25];
    const float* lwy1 = (const float*)d_in[26];
    const float* lby1 = (const float*)d_in[27];
    const float* lwy2 = (const float*)d_in[28];
    const float* lby2 = (const float*)d_in[29];
    const float* lwy3 = (const float*)d_in[30];
    const float* lby3 = (const float*)d_in[31];

    const int N = NODES, E = EDGES, N2 = 2*NODES;
    char* ws = (char*)d_ws;
    size_t off = 0;
    auto alloc = [&](size_t bytes)->char*{
        size_t a = (off + 255) & ~(size_t)255;
        off = a + bytes;
        return ws + a;
    };
    int* rowptr = (int*)alloc((size_t)(N2+1)*4);
    int* cursor = (int*)alloc((size_t)N2*4);
    int* counts = (int*)alloc((size_t)N2*4);
    int* colidx = (int*)alloc((size_t)2*E*4);
    short* xinh = (short*)alloc((size_t)N2*256*2);
    short* xinl = (short*)alloc((size_t)N2*256*2);
    float* xp   = (float*)alloc((size_t)N2*512*4);
    float* als1 = (float*)alloc((size_t)N2*2*4);
    float* ald1 = (float*)alloc((size_t)N2*2*4);
    short* bufAh = (short*)alloc((size_t)N2*512*2);
    short* bufAl = (short*)alloc((size_t)N2*512*2);
    float* xp2  = (float*)alloc((size_t)N2*256*4);
    float* als2 = (float*)alloc((size_t)N2*4);
    float* ald2 = (float*)alloc((size_t)N2*4);
    short* bufBh = (short*)alloc((size_t)N2*256*2);
    short* bufBl = (short*)alloc((size_t)N2*256*2);
    short* m1h = (short*)alloc((size_t)N2*256*2);
    short* m1l = (short*)alloc((size_t)N2*256*2);
    short* m2h = (short*)alloc((size_t)N2*128*2);
    short* m2l = (short*)alloc((size_t)N2*128*2);
    short* m3h = (short*)alloc((size_t)N2*64*2);
    short* m3l = (short*)alloc((size_t)N2*64*2);
    float* wt1s = (float*)alloc((size_t)2*256*2*4);
    float* wt1d = (float*)alloc((size_t)2*256*2*4);
    float* wt2s = (float*)alloc((size_t)2*512*4);
    float* wt2d = (float*)alloc((size_t)2*512*4);
    auto sal = [&](size_t n)->short*{ return (short*)alloc(n*2); };
    short* w1h0 = sal(512*256), *w1l0 = sal(512*256), *w1h1 = sal(512*256), *w1l1 = sal(512*256);
    short* w2h0 = sal(256*512), *w2l0 = sal(256*512), *w2h1 = sal(256*512), *w2l1 = sal(256*512);
    short* l1h0 = sal(256*256), *l1l0 = sal(256*256), *l1h1 = sal(256*256), *l1l1 = sal(256*256);
    short* l2h0 = sal(128*256), *l2l0 = sal(128*256), *l2h1 = sal(128*256), *l2l1 = sal(128*256);
    short* l3h0 = sal(64*128),  *l3l0 = sal(64*128),  *l3h1 = sal(64*128),  *l3l1 = sal(64*128);

    // --- zero accumulators / counts ---
    hipMemsetAsync(counts, 0, (size_t)N2*4, stream);
    hipMemsetAsync(als2, 0, (size_t)N2*4, stream);
    hipMemsetAsync(ald2, 0, (size_t)N2*4, stream);

    // --- CSR (both graphs) ---
    count2_kernel<<<(2*E+255)/256, 256, 0, stream>>>(eix, eiy, counts);
    scan_kernel<<<1, 1024, 0, stream>>>(counts, rowptr, N2);
    hipMemcpyAsync(cursor, rowptr, (size_t)N2*4, hipMemcpyDeviceToDevice, stream);
    fill2_kernel<<<(2*E+255)/256, 256, 0, stream>>>(eix, eiy, cursor, colidx);

    // --- w~ ---
    WtJobs wj;
    wj.j[0] = {Wx1, ax1s, wt1s,         256, 2, 0};
    wj.j[1] = {Wx1, ax1s, wt1s,         256, 2, 1};
    wj.j[2] = {Wx1, ax1d, wt1d,         256, 2, 0};
    wj.j[3] = {Wx1, ax1d, wt1d,         256, 2, 1};
    wj.j[4] = {Wy1, ay1s, wt1s+256*2,   256, 2, 0};
    wj.j[5] = {Wy1, ay1s, wt1s+256*2,   256, 2, 1};
    wj.j[6] = {Wy1, ay1d, wt1d+256*2,   256, 2, 0};
    wj.j[7] = {Wy1, ay1d, wt1d+256*2,   256, 2, 1};
    wj.j[8] = {Wx2, ax2s, wt2s,         512, 1, 0};
    wj.j[9] = {Wx2, ax2d, wt2d,         512, 1, 0};
    wj.j[10]= {Wy2, ay2s, wt2s+512,     512, 1, 0};
    wj.j[11]= {Wy2, ay2d, wt2d+512,     512, 1, 0};
    wtilde_kernel<<<12, 256, 0, stream>>>(wj);

    // --- weight transpose+split ---
    StJobs sj;
    sj.j[0] = {Wx1,  w1h0, w1l0, 256, 512};
    sj.j[1] = {Wy1,  w1h1, w1l1, 256, 512};
    sj.j[2] = {Wx2,  w2h0, w2l0, 512, 256};
    sj.j[3] = {Wy2,  w2h1, w2l1, 512, 256};
    sj.j[4] = {lwx1, l1h0, l1l0, 256, 256};
    sj.j[5] = {lwy1, l1h1, l1l1, 256, 256};
    sj.j[6] = {lwx2, l2h0, l2l0, 256, 128};
    sj.j[7] = {lwy2, l2h1, l2l1, 256, 128};
    sj.j[8] = {lwx3, l3h0, l3l0, 128, 64};
    sj.j[9] = {lwy3, l3h1, l3l1, 128, 64};
    splitT_batch<<<dim3(16,16,10), dim3(32,8), 0, stream>>>(sj);

    // --- input split + fused layer-1 logits ---
    split_in2<<<(N2+3)/4, 256, 0, stream>>>(x_m, x_d, wt1s, wt1d, xinh, xinl, als1, ald1);

    GemmJob jz = {nullptr,nullptr,nullptr,nullptr,nullptr,nullptr,nullptr,nullptr};

    // --- layer 1 GEMM: [2N,256] @ [512,256]^T -> xp [2N,512] fp32 ---
    {
        GemmJob a = {xinh, xinl, w1h0, w1l0, xp, nullptr, nullptr, nullptr};
        GemmJob b = {xinh + (size_t)N*256, xinl + (size_t)N*256, w1h1, w1l1,
                     xp + (size_t)N*512, nullptr, nullptr, nullptr};
        gemm_ps<<<dim3(8, (N+95)/96, 2), 256, 0, stream>>>(a, b, N, 512, 256, 0);
    }
    // --- GAT1 aggregation (fused softmax + als2 dot) ---
    agg_fused<512,2,1><<<(N2*2+3)/4, 256, 0, stream>>>(xp, als1, ald1, rowptr, colidx,
            bx1, by1, bufAh, bufAl, wt2s, wt2d, als2, ald2);
    // --- layer 2 GEMM: [2N,512] @ [256,512]^T -> xp2 [2N,256] fp32 ---
    {
        GemmJob a = {bufAh, bufAl, w2h0, w2l0, xp2, nullptr, nullptr, nullptr};
        GemmJob b = {bufAh + (size_t)N*512, bufAl + (size_t)N*512, w2h1, w2l1,
                     xp2 + (size_t)N*256, nullptr, nullptr, nullptr};
        gemm_ps<<<dim3(4, (N+95)/96, 2), 256, 0, stream>>>(a, b, N, 256, 512, 0);
    }
    // --- GAT2 aggregation ---
    agg_fused<256,1,0><<<(N2+3)/4, 256, 0, stream>>>(xp2, als2, ald2, rowptr, colidx,
            bx2, by2, bufBh, bufBl, nullptr, nullptr, nullptr, nullptr);
    // --- MLP head ---
    {
        GemmJob a = {bufBh, bufBl, l1h0, l1l0, nullptr, m1h, m1l, lbx1};
        GemmJob b = {bufBh + (size_t)N*256, bufBl + (size_t)N*256, l1h1, l1l1,
                     nullptr, m1h + (size_t)N*256, m1l + (size_t)N*256, lby1};
        gemm_ps<<<dim3(4, (N+95)/96, 2), 256, 0, stream>>>(a, b, N, 256, 256, 1);
    }
    {
        GemmJob a = {m1h, m1l, l2h0, l2l0, nullptr, m2h, m2l, lbx2};
        GemmJob b = {m1h + (size_t)N*256, m1l + (size_t)N*256, l2h1, l2l1,
                     nullptr, m2h + (size_t)N*128, m2l + (size_t)N*128, lby2};
        gemm_ps<<<dim3(2, (N+95)/96, 2), 256, 0, stream>>>(a, b, N, 128, 256, 1);
    }
    {
        GemmJob a = {m2h, m2l, l3h0, l3l0, nullptr, m3h, m3l, lbx3};
        GemmJob b = {m2h + (size_t)N*128, m2l + (size_t)N*128, l3h1, l3l1,
                     nullptr, m3h + (size_t)N*64, m3l + (size_t)N*64, lby3};
        gemm_ps<<<dim3(1, (N+95)/96, 2), 256, 0, stream>>>(a, b, N, 64, 128, 1);
    }
    // --- final: d_out[M,D] = X @ Y^T ---
    {
        GemmJob a = {m3h, m3l, m3h + (size_t)N*64, m3l + (size_t)N*64,
                     (float*)d_out, nullptr, nullptr, nullptr};
        gemm_ps<<<dim3((N+63)/64, (N+95)/96, 1), 256, 0, stream>>>(a, jz, N, N, 64, 0);
    }
}